// Round 9
// baseline (137.516 us; speedup 1.0000x reference)
//
#include <hip/hip_runtime.h>
#include <math.h>

// Capsule conv + dynamic routing via fp16 MFMA (16x16x32) — SINGLE dispatch.
// Operand swap vs R8: A = weights (M = f, K = tap*16+cin), B = input patch
// (N = px). Weights are read on the fly from the ORIGINAL fp32 layout
// (8 stride-512B dwords per fragment -> 4 full cache lines per wave-instr)
// and converted to fp16 in-register (RNE) — no prep kernel (2nd dispatch
// measured ~+30us wall across R3-R8; cooperative fusion fails graph capture, R7).
//
// x:    [B=32][H=32][W=32][128] fp32 (128 = i*16+cin)
// wts:  [i=8][k=144][o=128] fp32 (k = tap*16+cin, o = c*16+f)
// out:  [B][H][W][128] fp32
//
// Block = 1024 = 16 waves = (Mt 0..1) x (c 0..7); grid = 1024 (b*32+h).
// MFMA 16x16x32: A[m=lane&15 -> f][k=quad*8+j], B[k][n=lane&15 -> px].
// D layout: px = lane&15, f = quad*4 + reg  -> f in registers: squash/agreement
// reduce 4 in-reg + shfl_xor(16,32); route reads 1x(2 b128)/thread/iter;
// out store = per-lane float4.
// OCCUPANCY CLIFF: acc = 32 AGPRs (unified file); launch_bounds(1024,8) forces
// VGPR+AGPR <= 64 -> 2 blocks/CU. (R5: 68 regs silently halved residency.)

typedef _Float16 fp16x8 __attribute__((ext_vector_type(8)));
typedef float f32x4 __attribute__((ext_vector_type(4)));

#define EPS 1e-7f
constexpr int PSTRIDE = 136;   // fp16 elems; 272B row stride: 16B-aligned, 2-way banks (free)
constexpr int LSTRIDE = 76;    // lg_arr: [px*76 + i*9 + c]
constexpr int PXS     = 76;    // r_arr:  [px*76 + c*8 + i]; px b128 stride 304B -> 2-way (free)

// sum across the 4 quads (lanes ^16, ^32); all lanes receive the total
__device__ __forceinline__ float sumquad(float v) {
    v += __shfl_xor(v, 16);
    v += __shfl_xor(v, 32);
    return v;
}

__global__ __launch_bounds__(1024, 8)
void capsule_mfma_kernel(const float* __restrict__ x,
                         const float* __restrict__ wts,
                         const float* __restrict__ bias,
                         float* __restrict__ out)
{
    __shared__ _Float16 patch[3 * 34 * PSTRIDE];        // 27744 B
    __shared__ float lg_arr[32 * LSTRIDE];              // 9728 B
    __shared__ float r_arr[32 * PXS];                   // 9728 B

    const int tid  = threadIdx.x;
    const int lane = tid & 63;
    const int wv   = tid >> 6;
    const int c    = wv & 7;
    const int Mt   = wv >> 3;
    const int l15  = lane & 15;    // A-input: f ; B-input & D-output: px-in-tile
    const int quad = lane >> 4;

    const int bid = blockIdx.x;
    const int h = bid & 31, b = bid >> 5;

    // ---- stage input patch rows h-1..h+1, cols -1..32, fp16 ----
    const float4* x4 = (const float4*)x;
    for (int idx = tid; idx < 102 * 32; idx += 1024) {
        int ch4  = idx & 31;
        int slot = idx >> 5;
        int row  = slot / 34;
        int colp = slot - row * 34;
        int gh = h - 1 + row;
        int gw = colp - 1;
        float4 v = {0.f, 0.f, 0.f, 0.f};
        if ((unsigned)gh < 32u && (unsigned)gw < 32u)
            v = x4[(((b * 32 + gh) * 32 + gw) << 5) + ch4];
        _Float16 ph[4];
        ph[0] = (_Float16)v.x; ph[1] = (_Float16)v.y;
        ph[2] = (_Float16)v.z; ph[3] = (_Float16)v.w;
        *(ushort4*)&patch[slot * PSTRIDE + ch4 * 4] = *(const ushort4*)ph;
    }
    __syncthreads();

    // ---- B (patch) per-lane offsets: k = q*32 + quad*8 + j; tap = 2q+(quad>>1) ----
    int a_off[5];
    #pragma unroll
    for (int q = 0; q < 5; ++q) {
        int tap = 2 * q + (quad >> 1);
        if (tap > 8) tap = 8;                 // pad region: A is zeroed there
        int dy = tap / 3, dx = tap - dy * 3;
        a_off[q] = (dy * 34 + (Mt * 16 + l15 + dx)) * PSTRIDE + (quad & 1) * 8;
    }

    // ---- conv via MFMA: A-frag = weights fp32->fp16 on the fly ----
    f32x4 acc[8];
    #pragma unroll
    for (int i = 0; i < 8; ++i) acc[i] = (f32x4){0.f, 0.f, 0.f, 0.f};

    const float* wl = wts + quad * 8 * 128 + c * 16 + l15;   // + (i*144 + q*32 + j)*128
    #pragma unroll
    for (int q = 0; q < 5; ++q) {
        #pragma unroll
        for (int i = 0; i < 8; ++i) {
            const float* wp = wl + (i * 144 + q * 32) * 128;
            union { fp16x8 v; _Float16 e[8]; } aw;
            if (q < 4 || quad < 2) {          // k = q*32+quad*8+j < 144
                #pragma unroll
                for (int j = 0; j < 8; ++j) aw.e[j] = (_Float16)wp[j * 128];
            } else {
                #pragma unroll
                for (int j = 0; j < 8; ++j) aw.e[j] = (_Float16)0.f;
            }
            fp16x8 bh = *(const fp16x8*)(patch + a_off[q] + i * 16);
            acc[i] = __builtin_amdgcn_mfma_f32_16x16x32_f16(aw.v, bh, acc[i], 0, 0, 0);
        }
    }

    // ---- dynamic routing: thread owns (px = Mt*16+l15, c, f = quad*4 + 0..3) ----
    const float4 bb4 = *(const float4*)(bias + c * 16 + quad * 4);
    const float barr[4] = {bb4.x, bb4.y, bb4.z, bb4.w};
    const int px = Mt * 16 + l15;

    float pre[4], actv[4];

    // iter 0: route = 1/8 uniform
    #pragma unroll
    for (int r = 0; r < 4; ++r) {
        float s = acc[0][r] + acc[1][r] + acc[2][r] + acc[3][r]
                + acc[4][r] + acc[5][r] + acc[6][r] + acc[7][r];
        pre[r] = s * 0.125f + barr[r];
    }
    {
        float s2 = sumquad(pre[0]*pre[0] + pre[1]*pre[1] + pre[2]*pre[2] + pre[3]*pre[3]);
        float scale = s2 * __builtin_amdgcn_rsqf(s2 + EPS) * __builtin_amdgcn_rcpf(1.f + s2);
        #pragma unroll
        for (int r = 0; r < 4; ++r) actv[r] = scale * pre[r];
    }
    #pragma unroll
    for (int i = 0; i < 8; ++i) {
        float t = acc[i][0]*actv[0] + acc[i][1]*actv[1]
                + acc[i][2]*actv[2] + acc[i][3]*actv[3];
        t = sumquad(t);
        if (quad == 0) lg_arr[px * LSTRIDE + i * 9 + c] = t;
    }
    __syncthreads();
    if (tid < 256) {   // softmax over c for each (px, i)
        int p = tid >> 3, ii = tid & 7;
        const float* lrow = &lg_arr[p * LSTRIDE + ii * 9];
        float m = lrow[0];
        #pragma unroll
        for (int cc = 1; cc < 8; ++cc) m = fmaxf(m, lrow[cc]);
        float e[8]; float den = 0.f;
        #pragma unroll
        for (int cc = 0; cc < 8; ++cc) { e[cc] = __expf(lrow[cc] - m); den += e[cc]; }
        float rd = __builtin_amdgcn_rcpf(den);
        #pragma unroll
        for (int cc = 0; cc < 8; ++cc) r_arr[p * PXS + cc * 8 + ii] = e[cc] * rd;
    }
    __syncthreads();

    // iter 1
    {
        const float4* rp = (const float4*)&r_arr[px * PXS + c * 8];
        float4 r0 = rp[0], r1 = rp[1];
        #pragma unroll
        for (int r = 0; r < 4; ++r) {
            float s;
            s  = r0.x * acc[0][r]; s = fmaf(r0.y, acc[1][r], s);
            s  = fmaf(r0.z, acc[2][r], s); s = fmaf(r0.w, acc[3][r], s);
            s  = fmaf(r1.x, acc[4][r], s); s = fmaf(r1.y, acc[5][r], s);
            s  = fmaf(r1.z, acc[6][r], s); s = fmaf(r1.w, acc[7][r], s);
            pre[r] = s + barr[r];
        }
        float s2 = sumquad(pre[0]*pre[0] + pre[1]*pre[1] + pre[2]*pre[2] + pre[3]*pre[3]);
        float scale = s2 * __builtin_amdgcn_rsqf(s2 + EPS) * __builtin_amdgcn_rcpf(1.f + s2);
        #pragma unroll
        for (int r = 0; r < 4; ++r) actv[r] = scale * pre[r];
    }
    #pragma unroll
    for (int i = 0; i < 8; ++i) {
        float t = acc[i][0]*actv[0] + acc[i][1]*actv[1]
                + acc[i][2]*actv[2] + acc[i][3]*actv[3];
        t = sumquad(t);
        if (quad == 0) lg_arr[px * LSTRIDE + i * 9 + c] += t;
    }
    __syncthreads();
    if (tid < 256) {
        int p = tid >> 3, ii = tid & 7;
        const float* lrow = &lg_arr[p * LSTRIDE + ii * 9];
        float m = lrow[0];
        #pragma unroll
        for (int cc = 1; cc < 8; ++cc) m = fmaxf(m, lrow[cc]);
        float e[8]; float den = 0.f;
        #pragma unroll
        for (int cc = 0; cc < 8; ++cc) { e[cc] = __expf(lrow[cc] - m); den += e[cc]; }
        float rd = __builtin_amdgcn_rcpf(den);
        #pragma unroll
        for (int cc = 0; cc < 8; ++cc) r_arr[p * PXS + cc * 8 + ii] = e[cc] * rd;
    }
    __syncthreads();

    // iter 2: final activation -> out (per-lane float4: f = quad*4 + 0..3 consecutive)
    {
        const float4* rp = (const float4*)&r_arr[px * PXS + c * 8];
        float4 r0 = rp[0], r1 = rp[1];
        #pragma unroll
        for (int r = 0; r < 4; ++r) {
            float s;
            s  = r0.x * acc[0][r]; s = fmaf(r0.y, acc[1][r], s);
            s  = fmaf(r0.z, acc[2][r], s); s = fmaf(r0.w, acc[3][r], s);
            s  = fmaf(r1.x, acc[4][r], s); s = fmaf(r1.y, acc[5][r], s);
            s  = fmaf(r1.z, acc[6][r], s); s = fmaf(r1.w, acc[7][r], s);
            pre[r] = s + barr[r];
        }
        float s2 = sumquad(pre[0]*pre[0] + pre[1]*pre[1] + pre[2]*pre[2] + pre[3]*pre[3]);
        float scale = s2 * __builtin_amdgcn_rsqf(s2 + EPS) * __builtin_amdgcn_rcpf(1.f + s2);
        float4 o4 = { scale*pre[0], scale*pre[1], scale*pre[2], scale*pre[3] };
        *(float4*)(out + (((b * 32 + h) * 32 + px) << 7) + c * 16 + quad * 4) = o4;
    }
}

extern "C" void kernel_launch(void* const* d_in, const int* in_sizes, int n_in,
                              void* d_out, int out_size, void* d_ws, size_t ws_size,
                              hipStream_t stream) {
    const float* x    = (const float*)d_in[0];
    const float* wts  = (const float*)d_in[1];
    const float* bias = (const float*)d_in[2];
    float* out        = (float*)d_out;

    capsule_mfma_kernel<<<dim3(1024), dim3(1024), 0, stream>>>(x, wts, bias, out);
}

// Round 10
// 105.141 us; speedup vs baseline: 1.3079x; 1.3079x over previous
//
#include <hip/hip_runtime.h>
#include <math.h>

// Capsule conv + dynamic routing via fp16 MFMA (16x16x32), swapped operands:
// A = prepped fp16 weights (M = f), B = LDS input patch (N = px).
// Two dispatches: prep (fp32 -> lane-ordered fp16, ~9us wall incl. dispatch)
// then fused conv+routing. MFMA A and B operands share the same lane layout
// (m/n = lane&15, k = quad*8+j), so the R8 w16 buffer serves as A directly.
// NOTE: hipLaunchCooperativeKernel is NOT graph-capturable here (R7 failed);
// on-the-fly fp32 weight loads are latency-bound (R9: 320 scalar stride-512B
// loads -> VALUBusy 24%, main 85us). This combines R8's memory path with R9's
// cheap routing (D: px = lane&15, f = quad*4+reg -> f in registers).
//
// x:    [B=32][H=32][W=32][128] fp32 (128 = i*16+cin)
// wts:  [i=8][k=144][o=128] fp32 -> w16[(i*5+q)][c][lane][j]
//       = wts[(i*144 + q*32 + (lane>>4)*8 + j)*128 + c*16 + (lane&15)], 0 for k>=144
// out:  [B][H][W][128] fp32 (o = c*16+f)
//
// Block = 1024 = 16 waves = (Mt 0..1) x (c 0..7); grid = 1024 (b*32+h).
// OCCUPANCY CLIFF: acc = 32 AGPRs (unified file); launch_bounds(1024,8) forces
// VGPR+AGPR <= 64 -> 2 blocks/CU resident. (R5: 68 regs silently halved it.)

typedef _Float16 fp16x8 __attribute__((ext_vector_type(8)));
typedef float f32x4 __attribute__((ext_vector_type(4)));

#define EPS 1e-7f
constexpr int PSTRIDE = 136;   // fp16 elems; 272B row stride: 16B-aligned, 2-way banks (free)
constexpr int LSTRIDE = 76;    // lg_arr: [px*76 + i*9 + c]
constexpr int PXS     = 76;    // r_arr:  [px*76 + c*8 + i]; b128 quad-stride 304B -> 2-way (free)
constexpr int W_ELEMS = 40 * 8 * 64 * 8;   // 163840

// sum across the 4 quads (lanes ^16, ^32); all lanes receive the total
__device__ __forceinline__ float sumquad(float v) {
    v += __shfl_xor(v, 16);
    v += __shfl_xor(v, 32);
    return v;
}

// prep: direct scatter, 640 blocks x 256 threads, 1 element each (R8-proven).
__global__ __launch_bounds__(256)
void prep_weights(const float* __restrict__ wts,
                  _Float16* __restrict__ w16) {
    int n = blockIdx.x * 256 + threadIdx.x;        // 0..163839
    if (n >= W_ELEMS) return;
    int j    = n & 7;
    int ln   = (n >> 3) & 63;
    int c0   = (n >> 9) & 7;
    int iq   = n >> 12;                            // i*5+q
    int i0   = iq / 5;
    int q0   = iq - i0 * 5;
    int k = q0 * 32 + (ln >> 4) * 8 + j;
    float w = 0.f;
    if (k < 144) w = wts[(i0 * 144 + k) * 128 + c0 * 16 + (ln & 15)];
    w16[n] = (_Float16)w;                          // RNE
}

__global__ __launch_bounds__(1024, 8)
void capsule_mfma_kernel(const float* __restrict__ x,
                         const _Float16* __restrict__ w16,
                         const float* __restrict__ bias,
                         float* __restrict__ out)
{
    __shared__ _Float16 patch[3 * 34 * PSTRIDE];        // 27744 B
    __shared__ float lg_arr[32 * LSTRIDE];              // 9728 B
    __shared__ float r_arr[32 * PXS];                   // 9728 B

    const int tid  = threadIdx.x;
    const int lane = tid & 63;
    const int wv   = tid >> 6;
    const int c    = wv & 7;
    const int Mt   = wv >> 3;
    const int l15  = lane & 15;    // A: f ; B & D: px-in-tile
    const int quad = lane >> 4;
    const int lane8 = lane * 8;

    const int bid = blockIdx.x;
    const int h = bid & 31, b = bid >> 5;

    // ---- stage input patch rows h-1..h+1, cols -1..32, fp16 ----
    const float4* x4 = (const float4*)x;
    for (int idx = tid; idx < 102 * 32; idx += 1024) {
        int ch4  = idx & 31;
        int slot = idx >> 5;
        int row  = slot / 34;
        int colp = slot - row * 34;
        int gh = h - 1 + row;
        int gw = colp - 1;
        float4 v = {0.f, 0.f, 0.f, 0.f};
        if ((unsigned)gh < 32u && (unsigned)gw < 32u)
            v = x4[(((b * 32 + gh) * 32 + gw) << 5) + ch4];
        _Float16 ph[4];
        ph[0] = (_Float16)v.x; ph[1] = (_Float16)v.y;
        ph[2] = (_Float16)v.z; ph[3] = (_Float16)v.w;
        *(ushort4*)&patch[slot * PSTRIDE + ch4 * 4] = *(const ushort4*)ph;
    }
    __syncthreads();

    // ---- B (patch) per-lane offsets: k = q*32 + quad*8 + j; tap = 2q+(quad>>1) ----
    int a_off[5];
    #pragma unroll
    for (int q = 0; q < 5; ++q) {
        int tap = 2 * q + (quad >> 1);
        if (tap > 8) tap = 8;                 // pad region: A is zero there
        int dy = tap / 3, dx = tap - dy * 3;
        a_off[q] = (dy * 34 + (Mt * 16 + l15 + dx)) * PSTRIDE + (quad & 1) * 8;
    }

    // ---- conv via MFMA: 40 steps of (1 A b128 from L2, 1 B ds_read_b128, 1 MFMA) ----
    f32x4 acc[8];
    #pragma unroll
    for (int i = 0; i < 8; ++i) acc[i] = (f32x4){0.f, 0.f, 0.f, 0.f};

    #pragma unroll
    for (int q = 0; q < 5; ++q) {
        #pragma unroll
        for (int i = 0; i < 8; ++i) {
            int woff = ((i * 5 + q) * 8 + c) * 512 + lane8;
            fp16x8 aw = *(const fp16x8*)(w16 + woff);
            fp16x8 bh = *(const fp16x8*)(patch + a_off[q] + i * 16);
            acc[i] = __builtin_amdgcn_mfma_f32_16x16x32_f16(aw, bh, acc[i], 0, 0, 0);
        }
    }

    // ---- dynamic routing: thread owns (px = Mt*16+l15, c, f = quad*4 + 0..3) ----
    const float4 bb4 = *(const float4*)(bias + c * 16 + quad * 4);
    const float barr[4] = {bb4.x, bb4.y, bb4.z, bb4.w};
    const int px = Mt * 16 + l15;

    float pre[4], actv[4];

    // iter 0: route = 1/8 uniform
    #pragma unroll
    for (int r = 0; r < 4; ++r) {
        float s = acc[0][r] + acc[1][r] + acc[2][r] + acc[3][r]
                + acc[4][r] + acc[5][r] + acc[6][r] + acc[7][r];
        pre[r] = s * 0.125f + barr[r];
    }
    {
        float s2 = sumquad(pre[0]*pre[0] + pre[1]*pre[1] + pre[2]*pre[2] + pre[3]*pre[3]);
        float scale = s2 * __builtin_amdgcn_rsqf(s2 + EPS) * __builtin_amdgcn_rcpf(1.f + s2);
        #pragma unroll
        for (int r = 0; r < 4; ++r) actv[r] = scale * pre[r];
    }
    #pragma unroll
    for (int i = 0; i < 8; ++i) {
        float t = acc[i][0]*actv[0] + acc[i][1]*actv[1]
                + acc[i][2]*actv[2] + acc[i][3]*actv[3];
        t = sumquad(t);
        if (quad == 0) lg_arr[px * LSTRIDE + i * 9 + c] = t;
    }
    __syncthreads();
    if (tid < 256) {   // softmax over c for each (px, i)
        int p = tid >> 3, ii = tid & 7;
        const float* lrow = &lg_arr[p * LSTRIDE + ii * 9];
        float m = lrow[0];
        #pragma unroll
        for (int cc = 1; cc < 8; ++cc) m = fmaxf(m, lrow[cc]);
        float e[8]; float den = 0.f;
        #pragma unroll
        for (int cc = 0; cc < 8; ++cc) { e[cc] = __expf(lrow[cc] - m); den += e[cc]; }
        float rd = __builtin_amdgcn_rcpf(den);
        #pragma unroll
        for (int cc = 0; cc < 8; ++cc) r_arr[p * PXS + cc * 8 + ii] = e[cc] * rd;
    }
    __syncthreads();

    // iter 1
    {
        const float4* rp = (const float4*)&r_arr[px * PXS + c * 8];
        float4 r0 = rp[0], r1 = rp[1];
        #pragma unroll
        for (int r = 0; r < 4; ++r) {
            float s;
            s  = r0.x * acc[0][r]; s = fmaf(r0.y, acc[1][r], s);
            s  = fmaf(r0.z, acc[2][r], s); s = fmaf(r0.w, acc[3][r], s);
            s  = fmaf(r1.x, acc[4][r], s); s = fmaf(r1.y, acc[5][r], s);
            s  = fmaf(r1.z, acc[6][r], s); s = fmaf(r1.w, acc[7][r], s);
            pre[r] = s + barr[r];
        }
        float s2 = sumquad(pre[0]*pre[0] + pre[1]*pre[1] + pre[2]*pre[2] + pre[3]*pre[3]);
        float scale = s2 * __builtin_amdgcn_rsqf(s2 + EPS) * __builtin_amdgcn_rcpf(1.f + s2);
        #pragma unroll
        for (int r = 0; r < 4; ++r) actv[r] = scale * pre[r];
    }
    #pragma unroll
    for (int i = 0; i < 8; ++i) {
        float t = acc[i][0]*actv[0] + acc[i][1]*actv[1]
                + acc[i][2]*actv[2] + acc[i][3]*actv[3];
        t = sumquad(t);
        if (quad == 0) lg_arr[px * LSTRIDE + i * 9 + c] += t;
    }
    __syncthreads();
    if (tid < 256) {
        int p = tid >> 3, ii = tid & 7;
        const float* lrow = &lg_arr[p * LSTRIDE + ii * 9];
        float m = lrow[0];
        #pragma unroll
        for (int cc = 1; cc < 8; ++cc) m = fmaxf(m, lrow[cc]);
        float e[8]; float den = 0.f;
        #pragma unroll
        for (int cc = 0; cc < 8; ++cc) { e[cc] = __expf(lrow[cc] - m); den += e[cc]; }
        float rd = __builtin_amdgcn_rcpf(den);
        #pragma unroll
        for (int cc = 0; cc < 8; ++cc) r_arr[p * PXS + cc * 8 + ii] = e[cc] * rd;
    }
    __syncthreads();

    // iter 2: final activation -> out (per-lane float4: f = quad*4 + 0..3)
    {
        const float4* rp = (const float4*)&r_arr[px * PXS + c * 8];
        float4 r0 = rp[0], r1 = rp[1];
        #pragma unroll
        for (int r = 0; r < 4; ++r) {
            float s;
            s  = r0.x * acc[0][r]; s = fmaf(r0.y, acc[1][r], s);
            s  = fmaf(r0.z, acc[2][r], s); s = fmaf(r0.w, acc[3][r], s);
            s  = fmaf(r1.x, acc[4][r], s); s = fmaf(r1.y, acc[5][r], s);
            s  = fmaf(r1.z, acc[6][r], s); s = fmaf(r1.w, acc[7][r], s);
            pre[r] = s + barr[r];
        }
        float s2 = sumquad(pre[0]*pre[0] + pre[1]*pre[1] + pre[2]*pre[2] + pre[3]*pre[3]);
        float scale = s2 * __builtin_amdgcn_rsqf(s2 + EPS) * __builtin_amdgcn_rcpf(1.f + s2);
        float4 o4 = { scale*pre[0], scale*pre[1], scale*pre[2], scale*pre[3] };
        *(float4*)(out + (((b * 32 + h) * 32 + px) << 7) + c * 16 + quad * 4) = o4;
    }
}

extern "C" void kernel_launch(void* const* d_in, const int* in_sizes, int n_in,
                              void* d_out, int out_size, void* d_ws, size_t ws_size,
                              hipStream_t stream) {
    const float* x    = (const float*)d_in[0];
    const float* wts  = (const float*)d_in[1];
    const float* bias = (const float*)d_in[2];
    float* out        = (float*)d_out;
    _Float16* w16     = (_Float16*)d_ws;

    prep_weights<<<dim3(640), dim3(256), 0, stream>>>(wts, w16);
    capsule_mfma_kernel<<<dim3(1024), dim3(1024), 0, stream>>>(x, w16, bias, out);
}

// Round 11
// 103.923 us; speedup vs baseline: 1.3232x; 1.0117x over previous
//
#include <hip/hip_runtime.h>
#include <math.h>

// Capsule conv + dynamic routing via fp16 MFMA (16x16x32), swapped operands:
// A = prepped fp16 weights (M = f), B = LDS input patch (N = px).
// R11 change: 512-thread blocks (8 waves = 8 c, px-tile 16, grid 2048) so
// 4 independent blocks/CU de-phase the barrier/latency stalls that bound R10
// (1024-thr blocks, 2/CU, VALUBusy 30%: all waves stalled together).
// NOTE: hipLaunchCooperativeKernel is NOT graph-capturable here (R7 failed);
// on-the-fly fp32 weight loads are latency-bound (R9). Harness re-poison of
// d_ws (~44us fill) is fixed overhead we cannot remove.
//
// x:    [B=32][H=32][W=32][128] fp32 (128 = i*16+cin)
// wts:  [i=8][k=144][o=128] fp32 -> w16[(i*5+q)][c][lane][j]
//       = wts[(i*144 + q*32 + (lane>>4)*8 + j)*128 + c*16 + (lane&15)], 0 for k>=144
// out:  [B][H][W][128] fp32 (o = c*16+f)
//
// Block = 512 = 8 waves = c 0..7; grid = 2048 (b*64 + h*2 + half).
// MFMA 16x16x32: A[m=lane&15 -> f][k=quad*8+j], B[k][n=lane&15 -> px].
// D: px = lane&15, f = quad*4 + reg -> f in registers (cheap squash/agreement).
// OCCUPANCY CLIFF: acc = 32 AGPRs (unified file); launch_bounds(512,8) forces
// VGPR+AGPR <= 64 -> 8 waves/SIMD -> 4 blocks/CU. (R5: 68 regs halved residency.)

typedef _Float16 fp16x8 __attribute__((ext_vector_type(8)));
typedef float f32x4 __attribute__((ext_vector_type(4)));

#define EPS 1e-7f
constexpr int PSTRIDE = 136;   // fp16 elems; 272B row stride: 16B-aligned, 2-way banks (free)
constexpr int PCOLS   = 18;    // 16 px + 2 halo
constexpr int LSTRIDE = 76;    // lg_arr: [px*76 + i*9 + c]
constexpr int PXS     = 76;    // r_arr:  [px*76 + c*8 + i]; b128 stride 304B -> 2-way (free)
constexpr int W_ELEMS = 40 * 8 * 64 * 8;   // 163840

// sum across the 4 quads (lanes ^16, ^32); all lanes receive the total
__device__ __forceinline__ float sumquad(float v) {
    v += __shfl_xor(v, 16);
    v += __shfl_xor(v, 32);
    return v;
}

// prep: direct scatter, 640 blocks x 256 threads, 1 element each (R8-proven).
__global__ __launch_bounds__(256)
void prep_weights(const float* __restrict__ wts,
                  _Float16* __restrict__ w16) {
    int n = blockIdx.x * 256 + threadIdx.x;        // 0..163839
    if (n >= W_ELEMS) return;
    int j    = n & 7;
    int ln   = (n >> 3) & 63;
    int c0   = (n >> 9) & 7;
    int iq   = n >> 12;                            // i*5+q
    int i0   = iq / 5;
    int q0   = iq - i0 * 5;
    int k = q0 * 32 + (ln >> 4) * 8 + j;
    float w = 0.f;
    if (k < 144) w = wts[(i0 * 144 + k) * 128 + c0 * 16 + (ln & 15)];
    w16[n] = (_Float16)w;                          // RNE
}

__global__ __launch_bounds__(512, 8)
void capsule_mfma_kernel(const float* __restrict__ x,
                         const _Float16* __restrict__ w16,
                         const float* __restrict__ bias,
                         float* __restrict__ out)
{
    __shared__ _Float16 patch[3 * PCOLS * PSTRIDE];     // 14688 B
    __shared__ float lg_arr[16 * LSTRIDE];              // 4864 B
    __shared__ float r_arr[16 * PXS];                   // 4864 B

    const int tid  = threadIdx.x;
    const int lane = tid & 63;
    const int c    = tid >> 6;     // wave = c
    const int l15  = lane & 15;    // A: f ; B & D: px-in-tile
    const int quad = lane >> 4;
    const int lane8 = lane * 8;

    const int bid  = blockIdx.x;
    const int half = bid & 1;
    const int h    = (bid >> 1) & 31;
    const int b    = bid >> 6;
    const int w0   = half * 16;

    // ---- stage input patch rows h-1..h+1, cols w0-1..w0+16, fp16 ----
    const float4* x4 = (const float4*)x;
    for (int idx = tid; idx < 3 * PCOLS * 32; idx += 512) {
        int ch4  = idx & 31;
        int slot = idx >> 5;               // 0..53 = row*18 + colp
        int row  = slot / PCOLS;
        int colp = slot - row * PCOLS;
        int gh = h - 1 + row;
        int gw = w0 - 1 + colp;
        float4 v = {0.f, 0.f, 0.f, 0.f};
        if ((unsigned)gh < 32u && (unsigned)gw < 32u)
            v = x4[(((b * 32 + gh) * 32 + gw) << 5) + ch4];
        _Float16 ph[4];
        ph[0] = (_Float16)v.x; ph[1] = (_Float16)v.y;
        ph[2] = (_Float16)v.z; ph[3] = (_Float16)v.w;
        *(ushort4*)&patch[slot * PSTRIDE + ch4 * 4] = *(const ushort4*)ph;
    }
    __syncthreads();

    // ---- B (patch) per-lane offsets: k = q*32 + quad*8 + j; tap = 2q+(quad>>1) ----
    int a_off[5];
    #pragma unroll
    for (int q = 0; q < 5; ++q) {
        int tap = 2 * q + (quad >> 1);
        if (tap > 8) tap = 8;                 // pad region: A is zero there
        int dy = tap / 3, dx = tap - dy * 3;
        a_off[q] = (dy * PCOLS + l15 + dx) * PSTRIDE + (quad & 1) * 8;
    }

    // ---- conv via MFMA: 40 steps of (1 A b128 from L2, 1 B ds_read_b128, 1 MFMA) ----
    f32x4 acc[8];
    #pragma unroll
    for (int i = 0; i < 8; ++i) acc[i] = (f32x4){0.f, 0.f, 0.f, 0.f};

    #pragma unroll
    for (int q = 0; q < 5; ++q) {
        #pragma unroll
        for (int i = 0; i < 8; ++i) {
            int woff = ((i * 5 + q) * 8 + c) * 512 + lane8;
            fp16x8 aw = *(const fp16x8*)(w16 + woff);
            fp16x8 bh = *(const fp16x8*)(patch + a_off[q] + i * 16);
            acc[i] = __builtin_amdgcn_mfma_f32_16x16x32_f16(aw, bh, acc[i], 0, 0, 0);
        }
    }

    // ---- dynamic routing: thread owns (px = l15, c, f = quad*4 + 0..3) ----
    const float4 bb4 = *(const float4*)(bias + c * 16 + quad * 4);
    const float barr[4] = {bb4.x, bb4.y, bb4.z, bb4.w};

    float pre[4], actv[4];

    // iter 0: route = 1/8 uniform
    #pragma unroll
    for (int r = 0; r < 4; ++r) {
        float s = acc[0][r] + acc[1][r] + acc[2][r] + acc[3][r]
                + acc[4][r] + acc[5][r] + acc[6][r] + acc[7][r];
        pre[r] = s * 0.125f + barr[r];
    }
    {
        float s2 = sumquad(pre[0]*pre[0] + pre[1]*pre[1] + pre[2]*pre[2] + pre[3]*pre[3]);
        float scale = s2 * __builtin_amdgcn_rsqf(s2 + EPS) * __builtin_amdgcn_rcpf(1.f + s2);
        #pragma unroll
        for (int r = 0; r < 4; ++r) actv[r] = scale * pre[r];
    }
    #pragma unroll
    for (int i = 0; i < 8; ++i) {
        float t = acc[i][0]*actv[0] + acc[i][1]*actv[1]
                + acc[i][2]*actv[2] + acc[i][3]*actv[3];
        t = sumquad(t);
        if (quad == 0) lg_arr[l15 * LSTRIDE + i * 9 + c] = t;
    }
    __syncthreads();
    if (tid < 128) {   // softmax over c for each (px, i)
        int p = tid >> 3, ii = tid & 7;
        const float* lrow = &lg_arr[p * LSTRIDE + ii * 9];
        float m = lrow[0];
        #pragma unroll
        for (int cc = 1; cc < 8; ++cc) m = fmaxf(m, lrow[cc]);
        float e[8]; float den = 0.f;
        #pragma unroll
        for (int cc = 0; cc < 8; ++cc) { e[cc] = __expf(lrow[cc] - m); den += e[cc]; }
        float rd = __builtin_amdgcn_rcpf(den);
        #pragma unroll
        for (int cc = 0; cc < 8; ++cc) r_arr[p * PXS + cc * 8 + ii] = e[cc] * rd;
    }
    __syncthreads();

    // iter 1
    {
        const float4* rp = (const float4*)&r_arr[l15 * PXS + c * 8];
        float4 r0 = rp[0], r1 = rp[1];
        #pragma unroll
        for (int r = 0; r < 4; ++r) {
            float s;
            s  = r0.x * acc[0][r]; s = fmaf(r0.y, acc[1][r], s);
            s  = fmaf(r0.z, acc[2][r], s); s = fmaf(r0.w, acc[3][r], s);
            s  = fmaf(r1.x, acc[4][r], s); s = fmaf(r1.y, acc[5][r], s);
            s  = fmaf(r1.z, acc[6][r], s); s = fmaf(r1.w, acc[7][r], s);
            pre[r] = s + barr[r];
        }
        float s2 = sumquad(pre[0]*pre[0] + pre[1]*pre[1] + pre[2]*pre[2] + pre[3]*pre[3]);
        float scale = s2 * __builtin_amdgcn_rsqf(s2 + EPS) * __builtin_amdgcn_rcpf(1.f + s2);
        #pragma unroll
        for (int r = 0; r < 4; ++r) actv[r] = scale * pre[r];
    }
    #pragma unroll
    for (int i = 0; i < 8; ++i) {
        float t = acc[i][0]*actv[0] + acc[i][1]*actv[1]
                + acc[i][2]*actv[2] + acc[i][3]*actv[3];
        t = sumquad(t);
        if (quad == 0) lg_arr[l15 * LSTRIDE + i * 9 + c] += t;
    }
    __syncthreads();
    if (tid < 128) {
        int p = tid >> 3, ii = tid & 7;
        const float* lrow = &lg_arr[p * LSTRIDE + ii * 9];
        float m = lrow[0];
        #pragma unroll
        for (int cc = 1; cc < 8; ++cc) m = fmaxf(m, lrow[cc]);
        float e[8]; float den = 0.f;
        #pragma unroll
        for (int cc = 0; cc < 8; ++cc) { e[cc] = __expf(lrow[cc] - m); den += e[cc]; }
        float rd = __builtin_amdgcn_rcpf(den);
        #pragma unroll
        for (int cc = 0; cc < 8; ++cc) r_arr[p * PXS + cc * 8 + ii] = e[cc] * rd;
    }
    __syncthreads();

    // iter 2: final activation -> out (per-lane float4: f = quad*4 + 0..3)
    {
        const float4* rp = (const float4*)&r_arr[l15 * PXS + c * 8];
        float4 r0 = rp[0], r1 = rp[1];
        #pragma unroll
        for (int r = 0; r < 4; ++r) {
            float s;
            s  = r0.x * acc[0][r]; s = fmaf(r0.y, acc[1][r], s);
            s  = fmaf(r0.z, acc[2][r], s); s = fmaf(r0.w, acc[3][r], s);
            s  = fmaf(r1.x, acc[4][r], s); s = fmaf(r1.y, acc[5][r], s);
            s  = fmaf(r1.z, acc[6][r], s); s = fmaf(r1.w, acc[7][r], s);
            pre[r] = s + barr[r];
        }
        float s2 = sumquad(pre[0]*pre[0] + pre[1]*pre[1] + pre[2]*pre[2] + pre[3]*pre[3]);
        float scale = s2 * __builtin_amdgcn_rsqf(s2 + EPS) * __builtin_amdgcn_rcpf(1.f + s2);
        float4 o4 = { scale*pre[0], scale*pre[1], scale*pre[2], scale*pre[3] };
        *(float4*)(out + (((b * 32 + h) * 32 + w0 + l15) << 7) + c * 16 + quad * 4) = o4;
    }
}

extern "C" void kernel_launch(void* const* d_in, const int* in_sizes, int n_in,
                              void* d_out, int out_size, void* d_ws, size_t ws_size,
                              hipStream_t stream) {
    const float* x    = (const float*)d_in[0];
    const float* wts  = (const float*)d_in[1];
    const float* bias = (const float*)d_in[2];
    float* out        = (float*)d_out;
    _Float16* w16     = (_Float16*)d_ws;

    prep_weights<<<dim3(640), dim3(256), 0, stream>>>(wts, w16);
    capsule_mfma_kernel<<<dim3(2048), dim3(512), 0, stream>>>(x, w16, bias, out);
}

// Round 12
// 102.756 us; speedup vs baseline: 1.3383x; 1.0114x over previous
//
#include <hip/hip_runtime.h>
#include <math.h>

// Capsule conv + dynamic routing via fp16 MFMA (16x16x32), swapped operands:
// A = prepped fp16 weights (M = f), B = LDS input patch (N = px).
// R12 change: each wave computes TWO px-tiles (Mt 0..1) per A-fragment ->
// weight L2 traffic halves (655->327 MB) and, with acc=64 AGPRs + ~60 free
// VGPRs (launch_bounds(512,4) -> 128-reg budget), the scheduler can hold many
// A-loads in flight (R10/R11 at the 64-reg cliff had ~no MLP: VALUBusy 30%,
// all pipes idle, main ~43us latency-bound on the w16 stream).
// NOTE: hipLaunchCooperativeKernel is NOT graph-capturable here (R7 failed);
// on-the-fly fp32 weight loads are latency-bound (R9). ~44us d_ws re-poison
// fill + ~12us restore/launch are fixed harness overhead.
//
// x:    [B=32][H=32][W=32][128] fp32 (128 = i*16+cin)
// wts:  [i=8][k=144][o=128] fp32 -> w16[(i*5+q)][c][lane][j]
//       = wts[(i*144 + q*32 + (lane>>4)*8 + j)*128 + c*16 + (lane&15)], 0 for k>=144
// out:  [B][H][W][128] fp32 (o = c*16+f)
//
// Block = 512 = 8 waves = c 0..7, full 32-px row; grid = 1024 (b*32+h).
// MFMA 16x16x32: A[m=lane&15 -> f][k=quad*8+j], B[k][n=lane&15 -> px(mt)].
// D: px = mt*16 + lane&15, f = quad*4 + reg -> f in registers.
// Occupancy: 2 blocks/CU (16 waves) — traded vs halved A-traffic + MLP.

typedef _Float16 fp16x8 __attribute__((ext_vector_type(8)));
typedef float f32x4 __attribute__((ext_vector_type(4)));

#define EPS 1e-7f
constexpr int PSTRIDE = 136;   // fp16 elems; 272B row stride: 16B-aligned, 2-way banks (free)
constexpr int PCOLS   = 34;    // 32 px + 2 halo
constexpr int LSTRIDE = 76;    // lg_arr: [px*76 + i*9 + c]
constexpr int PXS     = 76;    // r_arr:  [px*76 + c*8 + i]; b128 stride 304B -> 2-way (free)
constexpr int W_ELEMS = 40 * 8 * 64 * 8;   // 163840

// sum across the 4 quads (lanes ^16, ^32); all lanes receive the total
__device__ __forceinline__ float sumquad(float v) {
    v += __shfl_xor(v, 16);
    v += __shfl_xor(v, 32);
    return v;
}

// prep: direct scatter, 640 blocks x 256 threads, 1 element each (R8-proven).
__global__ __launch_bounds__(256)
void prep_weights(const float* __restrict__ wts,
                  _Float16* __restrict__ w16) {
    int n = blockIdx.x * 256 + threadIdx.x;        // 0..163839
    if (n >= W_ELEMS) return;
    int j    = n & 7;
    int ln   = (n >> 3) & 63;
    int c0   = (n >> 9) & 7;
    int iq   = n >> 12;                            // i*5+q
    int i0   = iq / 5;
    int q0   = iq - i0 * 5;
    int k = q0 * 32 + (ln >> 4) * 8 + j;
    float w = 0.f;
    if (k < 144) w = wts[(i0 * 144 + k) * 128 + c0 * 16 + (ln & 15)];
    w16[n] = (_Float16)w;                          // RNE
}

__global__ __launch_bounds__(512, 4)
void capsule_mfma_kernel(const float* __restrict__ x,
                         const _Float16* __restrict__ w16,
                         const float* __restrict__ bias,
                         float* __restrict__ out)
{
    __shared__ _Float16 patch[3 * PCOLS * PSTRIDE];     // 27744 B
    __shared__ float lg_arr[32 * LSTRIDE];              // 9728 B
    __shared__ float r_arr[32 * PXS];                   // 9728 B

    const int tid  = threadIdx.x;
    const int lane = tid & 63;
    const int c    = tid >> 6;     // wave = c
    const int l15  = lane & 15;    // A: f ; B & D: px-in-tile
    const int quad = lane >> 4;
    const int lane8 = lane * 8;

    const int bid = blockIdx.x;
    const int h = bid & 31, b = bid >> 5;

    // ---- stage input patch rows h-1..h+1, cols -1..32, fp16 ----
    const float4* x4 = (const float4*)x;
    for (int idx = tid; idx < 3 * PCOLS * 32; idx += 512) {
        int ch4  = idx & 31;
        int slot = idx >> 5;               // row*34 + colp
        int row  = slot / PCOLS;
        int colp = slot - row * PCOLS;
        int gh = h - 1 + row;
        int gw = colp - 1;
        float4 v = {0.f, 0.f, 0.f, 0.f};
        if ((unsigned)gh < 32u && (unsigned)gw < 32u)
            v = x4[(((b * 32 + gh) * 32 + gw) << 5) + ch4];
        _Float16 ph[4];
        ph[0] = (_Float16)v.x; ph[1] = (_Float16)v.y;
        ph[2] = (_Float16)v.z; ph[3] = (_Float16)v.w;
        *(ushort4*)&patch[slot * PSTRIDE + ch4 * 4] = *(const ushort4*)ph;
    }
    __syncthreads();

    // ---- B (patch) per-lane offsets: k = q*32 + quad*8 + j; tap = 2q+(quad>>1) ----
    int a_off[5];
    #pragma unroll
    for (int q = 0; q < 5; ++q) {
        int tap = 2 * q + (quad >> 1);
        if (tap > 8) tap = 8;                 // pad region: A is zero there
        int dy = tap / 3, dx = tap - dy * 3;
        a_off[q] = (dy * PCOLS + l15 + dx) * PSTRIDE + (quad & 1) * 8;
    }

    // ---- conv via MFMA: 40 steps of (1 A b128 from L2, 2 B ds_read, 2 MFMA) ----
    f32x4 acc[2][8];
    #pragma unroll
    for (int mt = 0; mt < 2; ++mt)
        #pragma unroll
        for (int i = 0; i < 8; ++i) acc[mt][i] = (f32x4){0.f, 0.f, 0.f, 0.f};

    #pragma unroll
    for (int q = 0; q < 5; ++q) {
        #pragma unroll
        for (int i = 0; i < 8; ++i) {
            int woff = ((i * 5 + q) * 8 + c) * 512 + lane8;
            fp16x8 aw = *(const fp16x8*)(w16 + woff);
            fp16x8 b0 = *(const fp16x8*)(patch + a_off[q] + i * 16);
            fp16x8 b1 = *(const fp16x8*)(patch + a_off[q] + 16 * PSTRIDE + i * 16);
            acc[0][i] = __builtin_amdgcn_mfma_f32_16x16x32_f16(aw, b0, acc[0][i], 0, 0, 0);
            acc[1][i] = __builtin_amdgcn_mfma_f32_16x16x32_f16(aw, b1, acc[1][i], 0, 0, 0);
        }
    }

    // ---- dynamic routing: thread owns (px = mt*16+l15, c, f = quad*4 + 0..3) ----
    const float4 bb4 = *(const float4*)(bias + c * 16 + quad * 4);
    const float barr[4] = {bb4.x, bb4.y, bb4.z, bb4.w};

    float actv[2][4];

    // iter 0: route = 1/8 uniform
    #pragma unroll
    for (int mt = 0; mt < 2; ++mt) {
        float pre[4];
        #pragma unroll
        for (int r = 0; r < 4; ++r) {
            float s = acc[mt][0][r] + acc[mt][1][r] + acc[mt][2][r] + acc[mt][3][r]
                    + acc[mt][4][r] + acc[mt][5][r] + acc[mt][6][r] + acc[mt][7][r];
            pre[r] = s * 0.125f + barr[r];
        }
        float s2 = sumquad(pre[0]*pre[0] + pre[1]*pre[1] + pre[2]*pre[2] + pre[3]*pre[3]);
        float scale = s2 * __builtin_amdgcn_rsqf(s2 + EPS) * __builtin_amdgcn_rcpf(1.f + s2);
        #pragma unroll
        for (int r = 0; r < 4; ++r) actv[mt][r] = scale * pre[r];
    }
    #pragma unroll
    for (int mt = 0; mt < 2; ++mt)
        #pragma unroll
        for (int i = 0; i < 8; ++i) {
            float t = acc[mt][i][0]*actv[mt][0] + acc[mt][i][1]*actv[mt][1]
                    + acc[mt][i][2]*actv[mt][2] + acc[mt][i][3]*actv[mt][3];
            t = sumquad(t);
            if (quad == 0) lg_arr[(mt * 16 + l15) * LSTRIDE + i * 9 + c] = t;
        }
    __syncthreads();
    if (tid < 256) {   // softmax over c for each (px, i)
        int p = tid >> 3, ii = tid & 7;
        const float* lrow = &lg_arr[p * LSTRIDE + ii * 9];
        float m = lrow[0];
        #pragma unroll
        for (int cc = 1; cc < 8; ++cc) m = fmaxf(m, lrow[cc]);
        float e[8]; float den = 0.f;
        #pragma unroll
        for (int cc = 0; cc < 8; ++cc) { e[cc] = __expf(lrow[cc] - m); den += e[cc]; }
        float rd = __builtin_amdgcn_rcpf(den);
        #pragma unroll
        for (int cc = 0; cc < 8; ++cc) r_arr[p * PXS + cc * 8 + ii] = e[cc] * rd;
    }
    __syncthreads();

    // iter 1
    #pragma unroll
    for (int mt = 0; mt < 2; ++mt) {
        const float4* rp = (const float4*)&r_arr[(mt * 16 + l15) * PXS + c * 8];
        float4 r0 = rp[0], r1 = rp[1];
        float pre[4];
        #pragma unroll
        for (int r = 0; r < 4; ++r) {
            float s;
            s  = r0.x * acc[mt][0][r]; s = fmaf(r0.y, acc[mt][1][r], s);
            s  = fmaf(r0.z, acc[mt][2][r], s); s = fmaf(r0.w, acc[mt][3][r], s);
            s  = fmaf(r1.x, acc[mt][4][r], s); s = fmaf(r1.y, acc[mt][5][r], s);
            s  = fmaf(r1.z, acc[mt][6][r], s); s = fmaf(r1.w, acc[mt][7][r], s);
            pre[r] = s + barr[r];
        }
        float s2 = sumquad(pre[0]*pre[0] + pre[1]*pre[1] + pre[2]*pre[2] + pre[3]*pre[3]);
        float scale = s2 * __builtin_amdgcn_rsqf(s2 + EPS) * __builtin_amdgcn_rcpf(1.f + s2);
        #pragma unroll
        for (int r = 0; r < 4; ++r) actv[mt][r] = scale * pre[r];
    }
    #pragma unroll
    for (int mt = 0; mt < 2; ++mt)
        #pragma unroll
        for (int i = 0; i < 8; ++i) {
            float t = acc[mt][i][0]*actv[mt][0] + acc[mt][i][1]*actv[mt][1]
                    + acc[mt][i][2]*actv[mt][2] + acc[mt][i][3]*actv[mt][3];
            t = sumquad(t);
            if (quad == 0) lg_arr[(mt * 16 + l15) * LSTRIDE + i * 9 + c] += t;
        }
    __syncthreads();
    if (tid < 256) {
        int p = tid >> 3, ii = tid & 7;
        const float* lrow = &lg_arr[p * LSTRIDE + ii * 9];
        float m = lrow[0];
        #pragma unroll
        for (int cc = 1; cc < 8; ++cc) m = fmaxf(m, lrow[cc]);
        float e[8]; float den = 0.f;
        #pragma unroll
        for (int cc = 0; cc < 8; ++cc) { e[cc] = __expf(lrow[cc] - m); den += e[cc]; }
        float rd = __builtin_amdgcn_rcpf(den);
        #pragma unroll
        for (int cc = 0; cc < 8; ++cc) r_arr[p * PXS + cc * 8 + ii] = e[cc] * rd;
    }
    __syncthreads();

    // iter 2: final activation -> out (per-lane float4: f = quad*4 + 0..3)
    #pragma unroll
    for (int mt = 0; mt < 2; ++mt) {
        const float4* rp = (const float4*)&r_arr[(mt * 16 + l15) * PXS + c * 8];
        float4 r0 = rp[0], r1 = rp[1];
        float pre[4];
        #pragma unroll
        for (int r = 0; r < 4; ++r) {
            float s;
            s  = r0.x * acc[mt][0][r]; s = fmaf(r0.y, acc[mt][1][r], s);
            s  = fmaf(r0.z, acc[mt][2][r], s); s = fmaf(r0.w, acc[mt][3][r], s);
            s  = fmaf(r1.x, acc[mt][4][r], s); s = fmaf(r1.y, acc[mt][5][r], s);
            s  = fmaf(r1.z, acc[mt][6][r], s); s = fmaf(r1.w, acc[mt][7][r], s);
            pre[r] = s + barr[r];
        }
        float s2 = sumquad(pre[0]*pre[0] + pre[1]*pre[1] + pre[2]*pre[2] + pre[3]*pre[3]);
        float scale = s2 * __builtin_amdgcn_rsqf(s2 + EPS) * __builtin_amdgcn_rcpf(1.f + s2);
        float4 o4 = { scale*pre[0], scale*pre[1], scale*pre[2], scale*pre[3] };
        int px = mt * 16 + l15;
        *(float4*)(out + (((b * 32 + h) * 32 + px) << 7) + c * 16 + quad * 4) = o4;
    }
}

extern "C" void kernel_launch(void* const* d_in, const int* in_sizes, int n_in,
                              void* d_out, int out_size, void* d_ws, size_t ws_size,
                              hipStream_t stream) {
    const float* x    = (const float*)d_in[0];
    const float* wts  = (const float*)d_in[1];
    const float* bias = (const float*)d_in[2];
    float* out        = (float*)d_out;
    _Float16* w16     = (_Float16*)d_ws;

    prep_weights<<<dim3(640), dim3(256), 0, stream>>>(wts, w16);
    capsule_mfma_kernel<<<dim3(1024), dim3(512), 0, stream>>>(x, w16, bias, out);
}